// Round 8
// baseline (490.867 us; speedup 1.0000x reference)
//
#include <hip/hip_runtime.h>

// B=8, T=64, N=512, D=64, K=8 heads, d=8.
// r8: multi-tile blocks. Evidence r0-r7: dur ≈ rounds x L with L ≈ 40us/block,
// but the static critical path is only ~5us -> per-block FIXED cost dominates.
// Each block now processes NT=4 consecutive n (1024 blocks, exactly 4
// resident/CU, one round), amortizing F 4x. Next tile's x/ste float4 loads
// are ISSUED before barrier 1 and PACKED after the FFN (T14 split) so the
// HBM round rides under attention+FFN.
// Body = r5/r3 form (passed @163us): stride-72 everywhere (r7's stride-64 vT
// was a 16-way epilogue-write conflict: 2.1M -> 7.3M conflict cycles).

#define Bb 8
#define Tt 64
#define Nn 512
#define Dd 64
#define NT 4

typedef unsigned short u16;
typedef unsigned int u32;
typedef __bf16 bf16x8 __attribute__((ext_vector_type(8)));
typedef float f32x4 __attribute__((ext_vector_type(4)));
typedef short s16x8 __attribute__((ext_vector_type(8)));
typedef u32 u32x4 __attribute__((ext_vector_type(4)));

// LDS stride in shorts: 72 = 36 dw == 4 (mod 32) -> bank-balanced b128 rows,
// rows 16B-aligned.
#define QS 72

// ws layout (u16): WtQ[64][128] @0, WtK @8192, WtV @16384,
//                  Wt1[64][64] @24576, Wt2 @28672. Total 32768 u16 = 64 KiB.
#define WSQ 0
#define WSK 8192
#define WSV 16384
#define WS1 24576
#define WS2 28672

__device__ inline u16 f2bf(float f) {             // fp32 -> bf16 RNE
    u32 x = __float_as_uint(f);
    x += 0x7fffu + ((x >> 16) & 1u);
    return (u16)(x >> 16);
}
__device__ inline bf16x8 ldf(const u16* p) { return *(const bf16x8*)p; }
__device__ inline bf16x8 zf8() {
    s16x8 z = {0, 0, 0, 0, 0, 0, 0, 0};
    return __builtin_bit_cast(bf16x8, z);
}
__device__ inline bf16x8 pack8(float4 a, float4 b) {
    s16x8 r;
    r[0] = (short)f2bf(a.x); r[1] = (short)f2bf(a.y);
    r[2] = (short)f2bf(a.z); r[3] = (short)f2bf(a.w);
    r[4] = (short)f2bf(b.x); r[5] = (short)f2bf(b.y);
    r[6] = (short)f2bf(b.z); r[7] = (short)f2bf(b.w);
    return __builtin_bit_cast(bf16x8, r);
}
// Token row permutation for kb storage (bits 5..0: b1 q1 q0 b0 r1 r0 ->
// b1 b0 q1 q0 r1 r0): score slot (ct,qd,r) then holds s = 8qd+4(ct&1)+r+32(ct>>1).
__device__ inline int kperm(int row) {
    return (row & 0x23) | ((row & 4) << 2) | ((row & 0x18) >> 1);
}

// 64x64 GEMM, low-pressure form (loads inside the c-loop; compiler schedules).
// A: registers (AREG, QKV) or LDS rows (FFN). B: global bf16 Wt[col][KD]
// (L2-hot). Wave w computes rows 16w..16w+15, 4 col-tiles.
// MODE 0: relu -> bf16 LDS row-major; MODE 1: relu -> bf16 LDS transposed
// (O[col][row], vectorized ushort4); MODE 2: no relu -> fp32 global
// (row stride N*D); MODE 3: relu -> bf16 LDS rows permuted by kperm (kb).
template<int KD, int MODE, bool AREG>
__device__ inline void gemm(const bf16x8* afr,
                            const u16* aLds, int As,
                            const u16* __restrict__ WtG,
                            const float* __restrict__ bias,
                            u16* O, int Os, float* G,
                            int w, int lane, float scale) {
    const int l15 = lane & 15, qd = lane >> 4;
    f32x4 acc[4] = {{0,0,0,0},{0,0,0,0},{0,0,0,0},{0,0,0,0}};
#pragma unroll
    for (int c = 0; c < KD / 32; ++c) {
        bf16x8 af = AREG ? afr[c]
                         : ldf(&aLds[(16 * w + l15) * As + c * 32 + qd * 8]);
#pragma unroll
        for (int ct = 0; ct < 4; ++ct) {
            bf16x8 bfr = *(const bf16x8*)&WtG[(16 * ct + l15) * KD + c * 32 + qd * 8];
            acc[ct] = __builtin_amdgcn_mfma_f32_16x16x32_bf16(af, bfr, acc[ct], 0, 0, 0);
        }
    }
#pragma unroll
    for (int ct = 0; ct < 4; ++ct) {
        const int col = 16 * ct + l15;
        const float bv = bias[col];
        if (MODE == 1) {
            ushort4 st;
            st.x = f2bf(fmaxf(acc[ct][0] + bv, 0.f) * scale);
            st.y = f2bf(fmaxf(acc[ct][1] + bv, 0.f) * scale);
            st.z = f2bf(fmaxf(acc[ct][2] + bv, 0.f) * scale);
            st.w = f2bf(fmaxf(acc[ct][3] + bv, 0.f) * scale);
            *(ushort4*)&O[col * Os + 16 * w + 4 * qd] = st;
        } else {
#pragma unroll
            for (int r = 0; r < 4; ++r) {
                const int row = 16 * w + 4 * qd + r;
                float v = acc[ct][r] + bv;
                if (MODE != 2) v = fmaxf(v, 0.f);
                v *= scale;
                if (MODE == 0)      O[row * Os + col] = f2bf(v);
                else if (MODE == 3) O[kperm(row) * Os + col] = f2bf(v);
                else                G[(size_t)row * (Nn * Dd) + col] = v;
            }
        }
    }
}

// One-time weight transpose+convert: Wt[c][k] = bf16(W[k][c]).
__global__ __launch_bounds__(256)
void prep_w(const float* __restrict__ Wq, const float* __restrict__ Wk,
            const float* __restrict__ Wv, const float* __restrict__ W1,
            const float* __restrict__ W2, u16* __restrict__ ws) {
    int i = blockIdx.x * 256 + threadIdx.x;
    if (i < 24576) {                       // Wq/Wk/Wv: [128][64] each
        int m = i >> 13;
        int r = i & 8191;                  // r = k*64 + c (coalesced read)
        int k = r >> 6, c = r & 63;
        const float* W = (m == 0) ? Wq : (m == 1) ? Wk : Wv;
        ws[m * 8192 + c * 128 + k] = f2bf(W[r]);
    } else if (i < 32768) {                // W1/W2: [64][64] each
        int j = i - 24576;
        int m = j >> 12;
        int r = j & 4095;
        int k = r >> 6, c = r & 63;
        const float* W = (m == 0) ? W1 : W2;
        ws[24576 + m * 4096 + c * 64 + k] = f2bf(W[r]);
    }
}

__global__ __launch_bounds__(256, 4)
void ta_fused_kernel(const float* __restrict__ x,  const float* __restrict__ ste,
                     const float* __restrict__ bq, const float* __restrict__ bk,
                     const float* __restrict__ bv, const float* __restrict__ b1,
                     const float* __restrict__ b2, const u16* __restrict__ ws,
                     float* __restrict__ out) {
    // LDS map (shorts), 18432 total = 36,864 B -> 4 blocks/CU:
    //   qb [64][72] @ 0      (FFN abuf overlays: strictly wave-local rows)
    //   kb [64][72] @ 4608   (kperm rows; cross-wave, guarded by barriers)
    //   vT [64][72] @ 9216   (vT[dim][s]; cross-wave, guarded by barriers)
    //   ao [64][72] @ 13824  (attention output, wave-local rows)
    __shared__ __align__(16) u16 sm[18432];
    u16* qb = sm;
    u16* kb = sm + 4608;
    u16* vT = sm + 9216;
    u16* ao = sm + 13824;

    const int tid  = threadIdx.x;
    const int w    = tid >> 6;
    const int lane = tid & 63;
    const int l15  = lane & 15, qd = lane >> 4;
    const int bid  = blockIdx.x;
    const int b  = bid >> 7;                 // 128 blocks per b
    const int n0 = (bid & 127) << 2;         // 4 consecutive n per block

    const int trow = 16 * w + l15;
    const float* xr0 = x   + (((size_t)b * Tt + trow) * Nn + n0) * Dd;
    const float* sr0 = ste + (((size_t)b * Tt + trow) * Nn + n0) * Dd;

    // ---- tile 0's A-fragments (concat(x,ste) row trow) -> registers ----
    bf16x8 af[4];
    {
        float4 a0 = *(const float4*)(xr0 + qd * 8);
        float4 a1 = *(const float4*)(xr0 + qd * 8 + 4);
        float4 a2 = *(const float4*)(xr0 + 32 + qd * 8);
        float4 a3 = *(const float4*)(xr0 + 32 + qd * 8 + 4);
        float4 s0 = *(const float4*)(sr0 + qd * 8);
        float4 s1 = *(const float4*)(sr0 + qd * 8 + 4);
        float4 s2 = *(const float4*)(sr0 + 32 + qd * 8);
        float4 s3 = *(const float4*)(sr0 + 32 + qd * 8 + 4);
        af[0] = pack8(a0, a1); af[1] = pack8(a2, a3);
        af[2] = pack8(s0, s1); af[3] = pack8(s2, s3);
    }

    float4 rx0, rx1, rx2, rx3, rs0, rs1, rs2, rs3;   // next-tile raw prefetch

#pragma unroll 1
    for (int it = 0; it < NT; ++it) {
        // ---- Phase 1: QKV (B-fragments from global bf16 Wt, L2-hot) ----
        // 1/sqrt(8) folded into q.
        gemm<128, 0, true>(af, nullptr, 0, ws + WSQ, bq, qb, QS, nullptr, w, lane,
                           0.35355339059327373f);
        gemm<128, 3, true>(af, nullptr, 0, ws + WSK, bk, kb, QS, nullptr, w, lane, 1.f);
        gemm<128, 1, true>(af, nullptr, 0, ws + WSV, bv, vT, QS, nullptr, w, lane, 1.f);
        // issue next tile's x/ste loads NOW; pack only after the FFN (the
        // vmcnt wait lands there, so HBM latency hides under attn+FFN)
        if (it < NT - 1) {
            const float* xr = xr0 + (it + 1) * Dd;
            const float* sr = sr0 + (it + 1) * Dd;
            rx0 = *(const float4*)(xr + qd * 8);
            rx1 = *(const float4*)(xr + qd * 8 + 4);
            rx2 = *(const float4*)(xr + 32 + qd * 8);
            rx3 = *(const float4*)(xr + 32 + qd * 8 + 4);
            rs0 = *(const float4*)(sr + qd * 8);
            rs1 = *(const float4*)(sr + qd * 8 + 4);
            rs2 = *(const float4*)(sr + 32 + qd * 8);
            rs3 = *(const float4*)(sr + 32 + qd * 8 + 4);
        }
        __syncthreads();   // barrier 1: kb/vT (cross-wave) now visible

        // ---- Phase 2: attention. Wave w owns t-rows 16w..16w+15, 8 heads.
        const bf16x8 z8 = zf8();
        const int ctmax = (w >= 2) ? 3 : 1;     // causal tile skip
#pragma unroll 1
        for (int h8 = 0; h8 < 64; h8 += 8) {
            // scores (swapped): sv[ct] = mfma(A=k-tile ct, B=q). Output col
            // l15 = t-local, slot (ct,qd,r) -> s = 8qd+4(ct&1)+r+32(ct>>1).
            bf16x8 qfr = (qd == 0) ? ldf(&qb[(16 * w + l15) * QS + h8]) : z8;
            f32x4 sv[4] = {{0,0,0,0},{0,0,0,0},{0,0,0,0},{0,0,0,0}};
#pragma unroll
            for (int ct = 0; ct < 4; ++ct) {
                if (ct <= ctmax) {
                    bf16x8 kfr = (qd == 0) ? ldf(&kb[(16 * ct + l15) * QS + h8]) : z8;
                    sv[ct] = __builtin_amdgcn_mfma_f32_16x16x32_bf16(kfr, qfr, sv[ct], 0, 0, 0);
                }
            }
            // mask + exp in-register; pack to bf16 pairs (P fragment).
            const int t = 16 * w + l15;
            float dsum = 0.f;
            u32 pk[8];
#pragma unroll
            for (int ct = 0; ct < 4; ++ct) {
                if (ct <= ctmax) {
                    const int sbase = 8 * qd + 4 * (ct & 1) + 32 * (ct >> 1);
#pragma unroll
                    for (int r = 0; r < 4; ++r) {
                        float e = (sbase + r <= t) ? __expf(sv[ct][r]) : 0.f;
                        sv[ct][r] = e;
                        dsum += e;
                    }
                    pk[2 * ct]     = (u32)f2bf(sv[ct][0]) | ((u32)f2bf(sv[ct][1]) << 16);
                    pk[2 * ct + 1] = (u32)f2bf(sv[ct][2]) | ((u32)f2bf(sv[ct][3]) << 16);
                } else {
                    pk[2 * ct] = 0; pk[2 * ct + 1] = 0;
                }
            }
            // row denominator: lane partial + cross-quad butterfly
            dsum += __shfl_xor(dsum, 16, 64);
            dsum += __shfl_xor(dsum, 32, 64);

            // PV (swapped): o = mfma(A = V^T slice, B = P^T); B col l15 = t
            // -> lane's own dsum normalizes its column.
            const int vrow = h8 + (l15 & 7);
            f32x4 o = {0, 0, 0, 0};
            {
                bf16x8 va0 = ldf(&vT[vrow * QS + 0 + qd * 8]);
                u32x4 pb0 = {pk[0], pk[1], pk[2], pk[3]};
                o = __builtin_amdgcn_mfma_f32_16x16x32_bf16(
                        va0, __builtin_bit_cast(bf16x8, pb0), o, 0, 0, 0);
            }
            if (w >= 2) {
                bf16x8 va1 = ldf(&vT[vrow * QS + 32 + qd * 8]);
                u32x4 pb1 = {pk[4], pk[5], pk[6], pk[7]};
                o = __builtin_amdgcn_mfma_f32_16x16x32_bf16(
                        va1, __builtin_bit_cast(bf16x8, pb1), o, 0, 0, 0);
            }
            // o[r] = out[t][h8+((4qd+r)&7)] unnorm.; qd>=2 duplicates qd-2.
            float invd = __builtin_amdgcn_rcpf(dsum);
            if (qd < 2) {
                ushort4 st;
                st.x = f2bf(o[0] * invd);
                st.y = f2bf(o[1] * invd);
                st.z = f2bf(o[2] * invd);
                st.w = f2bf(o[3] * invd);
                *(ushort4*)&ao[(16 * w + l15) * QS + h8 + 4 * qd] = st;
            }
        }
        __syncthreads();   // barrier 2: kb/vT dead for this tile; next tile's
                           // QKV epilogues (cross-wave kb/vT writes) are safe

        // ---- Phase 3: FFN (ao/abuf rows wave-local; no more barriers) ----
        u16* abuf = qb;
        gemm<64, 0, false>(nullptr, ao, QS, ws + WS1, b1, abuf, QS, nullptr,
                           w, lane, 1.f);
        float* ob = out + (((size_t)b * Tt) * Nn + (n0 + it)) * Dd;
        gemm<64, 2, false>(nullptr, abuf, QS, ws + WS2, b2, nullptr, 0, ob,
                           w, lane, 1.f);

        // pack prefetched raw -> af for next tile (vmcnt wait lands here)
        if (it < NT - 1) {
            af[0] = pack8(rx0, rx1); af[1] = pack8(rx2, rx3);
            af[2] = pack8(rs0, rs1); af[3] = pack8(rs2, rs3);
        }
    }
}

extern "C" void kernel_launch(void* const* d_in, const int* in_sizes, int n_in,
                              void* d_out, int out_size, void* d_ws, size_t ws_size,
                              hipStream_t stream) {
    const float* x   = (const float*)d_in[0];
    const float* ste = (const float*)d_in[1];
    const float* Wq  = (const float*)d_in[2];
    const float* bq  = (const float*)d_in[3];
    const float* Wk  = (const float*)d_in[4];
    const float* bk  = (const float*)d_in[5];
    const float* Wv  = (const float*)d_in[6];
    const float* bv  = (const float*)d_in[7];
    const float* W1  = (const float*)d_in[8];
    const float* b1  = (const float*)d_in[9];
    const float* W2  = (const float*)d_in[10];
    const float* b2  = (const float*)d_in[11];
    float* out = (float*)d_out;
    u16* ws = (u16*)d_ws;

    hipLaunchKernelGGL(prep_w, dim3(128), dim3(256), 0, stream,
                       Wq, Wk, Wv, W1, W2, ws);
    hipLaunchKernelGGL(ta_fused_kernel, dim3(Bb * Nn / NT), dim3(256), 0, stream,
                       x, ste, bq, bk, bv, b1, b2, ws, out);
}

// Round 9
// 440.515 us; speedup vs baseline: 1.1143x; 1.1143x over previous
//
#include <hip/hip_runtime.h>

// B=8, T=64, N=512, D=64, K=8 heads, d=8.
// r9: clean re-test of r8's fixed-cost amortization. r8 spilled because af[]
// was reassigned across loop iterations with its address taken (+8 live
// conditional prefetch float4s) -> scratch (FETCH 621MB). Fix: af declared
// FRESH inside each tile iteration, assigned once, no cross-iteration regs.
// Each block processes NT=4 consecutive n (grid 1024 = exactly 4/CU, one
// round). Body = r5's exact 163us-clean code; LDS map unchanged.

#define Bb 8
#define Tt 64
#define Nn 512
#define Dd 64
#define NT 4

typedef unsigned short u16;
typedef unsigned int u32;
typedef __bf16 bf16x8 __attribute__((ext_vector_type(8)));
typedef float f32x4 __attribute__((ext_vector_type(4)));
typedef short s16x8 __attribute__((ext_vector_type(8)));
typedef u32 u32x4 __attribute__((ext_vector_type(4)));

// LDS stride in shorts: 72 = 36 dw == 4 (mod 32) -> bank-balanced b128 rows,
// rows 16B-aligned.
#define QS 72

// ws layout (u16): WtQ[64][128] @0, WtK @8192, WtV @16384,
//                  Wt1[64][64] @24576, Wt2 @28672. Total 32768 u16 = 64 KiB.
#define WSQ 0
#define WSK 8192
#define WSV 16384
#define WS1 24576
#define WS2 28672

__device__ inline u16 f2bf(float f) {             // fp32 -> bf16 RNE
    u32 x = __float_as_uint(f);
    x += 0x7fffu + ((x >> 16) & 1u);
    return (u16)(x >> 16);
}
__device__ inline bf16x8 ldf(const u16* p) { return *(const bf16x8*)p; }
__device__ inline bf16x8 zf8() {
    s16x8 z = {0, 0, 0, 0, 0, 0, 0, 0};
    return __builtin_bit_cast(bf16x8, z);
}
__device__ inline bf16x8 pack8(float4 a, float4 b) {
    s16x8 r;
    r[0] = (short)f2bf(a.x); r[1] = (short)f2bf(a.y);
    r[2] = (short)f2bf(a.z); r[3] = (short)f2bf(a.w);
    r[4] = (short)f2bf(b.x); r[5] = (short)f2bf(b.y);
    r[6] = (short)f2bf(b.z); r[7] = (short)f2bf(b.w);
    return __builtin_bit_cast(bf16x8, r);
}
// Token row permutation for kb storage (bits 5..0: b1 q1 q0 b0 r1 r0 ->
// b1 b0 q1 q0 r1 r0): score slot (ct,qd,r) then holds s = 8qd+4(ct&1)+r+32(ct>>1).
__device__ inline int kperm(int row) {
    return (row & 0x23) | ((row & 4) << 2) | ((row & 0x18) >> 1);
}

// 64x64 GEMM, low-pressure form (loads inside the c-loop; compiler schedules).
// A: registers (AREG, QKV) or LDS rows (FFN). B: global bf16 Wt[col][KD]
// (L2-hot). Wave w computes rows 16w..16w+15, 4 col-tiles.
// MODE 0: relu -> bf16 LDS row-major; MODE 1: relu -> bf16 LDS transposed
// (O[col][row], vectorized ushort4); MODE 2: no relu -> fp32 global
// (row stride N*D); MODE 3: relu -> bf16 LDS rows permuted by kperm (kb).
template<int KD, int MODE, bool AREG>
__device__ inline void gemm(const bf16x8* afr,
                            const u16* aLds, int As,
                            const u16* __restrict__ WtG,
                            const float* __restrict__ bias,
                            u16* O, int Os, float* G,
                            int w, int lane, float scale) {
    const int l15 = lane & 15, qd = lane >> 4;
    f32x4 acc[4] = {{0,0,0,0},{0,0,0,0},{0,0,0,0},{0,0,0,0}};
#pragma unroll
    for (int c = 0; c < KD / 32; ++c) {
        bf16x8 af = AREG ? afr[c]
                         : ldf(&aLds[(16 * w + l15) * As + c * 32 + qd * 8]);
#pragma unroll
        for (int ct = 0; ct < 4; ++ct) {
            bf16x8 bfr = *(const bf16x8*)&WtG[(16 * ct + l15) * KD + c * 32 + qd * 8];
            acc[ct] = __builtin_amdgcn_mfma_f32_16x16x32_bf16(af, bfr, acc[ct], 0, 0, 0);
        }
    }
#pragma unroll
    for (int ct = 0; ct < 4; ++ct) {
        const int col = 16 * ct + l15;
        const float bv = bias[col];
        if (MODE == 1) {
            ushort4 st;
            st.x = f2bf(fmaxf(acc[ct][0] + bv, 0.f) * scale);
            st.y = f2bf(fmaxf(acc[ct][1] + bv, 0.f) * scale);
            st.z = f2bf(fmaxf(acc[ct][2] + bv, 0.f) * scale);
            st.w = f2bf(fmaxf(acc[ct][3] + bv, 0.f) * scale);
            *(ushort4*)&O[col * Os + 16 * w + 4 * qd] = st;
        } else {
#pragma unroll
            for (int r = 0; r < 4; ++r) {
                const int row = 16 * w + 4 * qd + r;
                float v = acc[ct][r] + bv;
                if (MODE != 2) v = fmaxf(v, 0.f);
                v *= scale;
                if (MODE == 0)      O[row * Os + col] = f2bf(v);
                else if (MODE == 3) O[kperm(row) * Os + col] = f2bf(v);
                else                G[(size_t)row * (Nn * Dd) + col] = v;
            }
        }
    }
}

// One-time weight transpose+convert: Wt[c][k] = bf16(W[k][c]).
__global__ __launch_bounds__(256)
void prep_w(const float* __restrict__ Wq, const float* __restrict__ Wk,
            const float* __restrict__ Wv, const float* __restrict__ W1,
            const float* __restrict__ W2, u16* __restrict__ ws) {
    int i = blockIdx.x * 256 + threadIdx.x;
    if (i < 24576) {                       // Wq/Wk/Wv: [128][64] each
        int m = i >> 13;
        int r = i & 8191;                  // r = k*64 + c (coalesced read)
        int k = r >> 6, c = r & 63;
        const float* W = (m == 0) ? Wq : (m == 1) ? Wk : Wv;
        ws[m * 8192 + c * 128 + k] = f2bf(W[r]);
    } else if (i < 32768) {                // W1/W2: [64][64] each
        int j = i - 24576;
        int m = j >> 12;
        int r = j & 4095;
        int k = r >> 6, c = r & 63;
        const float* W = (m == 0) ? W1 : W2;
        ws[24576 + m * 4096 + c * 64 + k] = f2bf(W[r]);
    }
}

__global__ __launch_bounds__(256, 4)
void ta_fused_kernel(const float* __restrict__ x,  const float* __restrict__ ste,
                     const float* __restrict__ bq, const float* __restrict__ bk,
                     const float* __restrict__ bv, const float* __restrict__ b1,
                     const float* __restrict__ b2, const u16* __restrict__ ws,
                     float* __restrict__ out) {
    // LDS map (shorts), 18432 total = 36,864 B -> 4 blocks/CU:
    //   qb [64][72] @ 0      (always wave-local rows: attn reads own rows,
    //                         FFN abuf overlays own rows, QKV writes own rows)
    //   kb [64][72] @ 4608   (kperm rows; cross-wave, guarded by barriers)
    //   vT [64][72] @ 9216   (vT[dim][s]; cross-wave, guarded by barriers)
    //   ao [64][72] @ 13824  (attention output, wave-local rows)
    __shared__ __align__(16) u16 sm[18432];
    u16* qb = sm;
    u16* kb = sm + 4608;
    u16* vT = sm + 9216;
    u16* ao = sm + 13824;

    const int tid  = threadIdx.x;
    const int w    = tid >> 6;
    const int lane = tid & 63;
    const int l15  = lane & 15, qd = lane >> 4;
    const int bid  = blockIdx.x;
    const int b  = bid >> 7;                 // 128 blocks per b
    const int n0 = (bid & 127) << 2;         // 4 consecutive n per block

    const int trow = 16 * w + l15;
    const float* xr0 = x   + (((size_t)b * Tt + trow) * Nn + n0) * Dd;
    const float* sr0 = ste + (((size_t)b * Tt + trow) * Nn + n0) * Dd;

#pragma unroll 1
    for (int it = 0; it < NT; ++it) {
        // ---- Phase 0: this tile's A-fragments -> registers (fresh scope,
        //      single assignment: promotes to VGPRs, no scratch) ----
        bf16x8 af[4];
        {
            const float* xr = xr0 + it * Dd;
            const float* sr = sr0 + it * Dd;
            float4 a0 = *(const float4*)(xr + qd * 8);
            float4 a1 = *(const float4*)(xr + qd * 8 + 4);
            float4 a2 = *(const float4*)(xr + 32 + qd * 8);
            float4 a3 = *(const float4*)(xr + 32 + qd * 8 + 4);
            float4 s0 = *(const float4*)(sr + qd * 8);
            float4 s1 = *(const float4*)(sr + qd * 8 + 4);
            float4 s2 = *(const float4*)(sr + 32 + qd * 8);
            float4 s3 = *(const float4*)(sr + 32 + qd * 8 + 4);
            af[0] = pack8(a0, a1); af[1] = pack8(a2, a3);
            af[2] = pack8(s0, s1); af[3] = pack8(s2, s3);
        }

        // ---- Phase 1: QKV (B-fragments from global bf16 Wt, L2-hot) ----
        // 1/sqrt(8) folded into q.
        gemm<128, 0, true>(af, nullptr, 0, ws + WSQ, bq, qb, QS, nullptr, w, lane,
                           0.35355339059327373f);
        gemm<128, 3, true>(af, nullptr, 0, ws + WSK, bk, kb, QS, nullptr, w, lane, 1.f);
        gemm<128, 1, true>(af, nullptr, 0, ws + WSV, bv, vT, QS, nullptr, w, lane, 1.f);
        __syncthreads();   // barrier 1: kb/vT (cross-wave) now visible

        // ---- Phase 2: attention. Wave w owns t-rows 16w..16w+15, 8 heads.
        const bf16x8 z8 = zf8();
        const int ctmax = (w >= 2) ? 3 : 1;     // causal tile skip
#pragma unroll 1
        for (int h8 = 0; h8 < 64; h8 += 8) {
            // scores (swapped): sv[ct] = mfma(A=k-tile ct, B=q). Output col
            // l15 = t-local, slot (ct,qd,r) -> s = 8qd+4(ct&1)+r+32(ct>>1).
            bf16x8 qfr = (qd == 0) ? ldf(&qb[(16 * w + l15) * QS + h8]) : z8;
            f32x4 sv[4] = {{0,0,0,0},{0,0,0,0},{0,0,0,0},{0,0,0,0}};
#pragma unroll
            for (int ct = 0; ct < 4; ++ct) {
                if (ct <= ctmax) {
                    bf16x8 kfr = (qd == 0) ? ldf(&kb[(16 * ct + l15) * QS + h8]) : z8;
                    sv[ct] = __builtin_amdgcn_mfma_f32_16x16x32_bf16(kfr, qfr, sv[ct], 0, 0, 0);
                }
            }
            // mask + exp in-register; pack to bf16 pairs (P fragment).
            const int t = 16 * w + l15;
            float dsum = 0.f;
            u32 pk[8];
#pragma unroll
            for (int ct = 0; ct < 4; ++ct) {
                if (ct <= ctmax) {
                    const int sbase = 8 * qd + 4 * (ct & 1) + 32 * (ct >> 1);
#pragma unroll
                    for (int r = 0; r < 4; ++r) {
                        float e = (sbase + r <= t) ? __expf(sv[ct][r]) : 0.f;
                        sv[ct][r] = e;
                        dsum += e;
                    }
                    pk[2 * ct]     = (u32)f2bf(sv[ct][0]) | ((u32)f2bf(sv[ct][1]) << 16);
                    pk[2 * ct + 1] = (u32)f2bf(sv[ct][2]) | ((u32)f2bf(sv[ct][3]) << 16);
                } else {
                    pk[2 * ct] = 0; pk[2 * ct + 1] = 0;
                }
            }
            // row denominator: lane partial + cross-quad butterfly
            dsum += __shfl_xor(dsum, 16, 64);
            dsum += __shfl_xor(dsum, 32, 64);

            // PV (swapped): o = mfma(A = V^T slice, B = P^T); B col l15 = t
            // -> lane's own dsum normalizes its column.
            const int vrow = h8 + (l15 & 7);
            f32x4 o = {0, 0, 0, 0};
            {
                bf16x8 va0 = ldf(&vT[vrow * QS + 0 + qd * 8]);
                u32x4 pb0 = {pk[0], pk[1], pk[2], pk[3]};
                o = __builtin_amdgcn_mfma_f32_16x16x32_bf16(
                        va0, __builtin_bit_cast(bf16x8, pb0), o, 0, 0, 0);
            }
            if (w >= 2) {
                bf16x8 va1 = ldf(&vT[vrow * QS + 32 + qd * 8]);
                u32x4 pb1 = {pk[4], pk[5], pk[6], pk[7]};
                o = __builtin_amdgcn_mfma_f32_16x16x32_bf16(
                        va1, __builtin_bit_cast(bf16x8, pb1), o, 0, 0, 0);
            }
            // o[r] = out[t][h8+((4qd+r)&7)] unnorm.; qd>=2 duplicates qd-2.
            float invd = __builtin_amdgcn_rcpf(dsum);
            if (qd < 2) {
                ushort4 st;
                st.x = f2bf(o[0] * invd);
                st.y = f2bf(o[1] * invd);
                st.z = f2bf(o[2] * invd);
                st.w = f2bf(o[3] * invd);
                *(ushort4*)&ao[(16 * w + l15) * QS + h8 + 4 * qd] = st;
            }
        }
        __syncthreads();   // barrier 2: kb/vT reads done; next tile's QKV
                           // epilogues (cross-wave kb/vT writes) are safe

        // ---- Phase 3: FFN (ao/abuf rows wave-local; no more barriers) ----
        u16* abuf = qb;
        gemm<64, 0, false>(nullptr, ao, QS, ws + WS1, b1, abuf, QS, nullptr,
                           w, lane, 1.f);
        float* ob = out + (((size_t)b * Tt) * Nn + (n0 + it)) * Dd;
        gemm<64, 2, false>(nullptr, abuf, QS, ws + WS2, b2, nullptr, 0, ob,
                           w, lane, 1.f);
    }
}

extern "C" void kernel_launch(void* const* d_in, const int* in_sizes, int n_in,
                              void* d_out, int out_size, void* d_ws, size_t ws_size,
                              hipStream_t stream) {
    const float* x   = (const float*)d_in[0];
    const float* ste = (const float*)d_in[1];
    const float* Wq  = (const float*)d_in[2];
    const float* bq  = (const float*)d_in[3];
    const float* Wk  = (const float*)d_in[4];
    const float* bk  = (const float*)d_in[5];
    const float* Wv  = (const float*)d_in[6];
    const float* bv  = (const float*)d_in[7];
    const float* W1  = (const float*)d_in[8];
    const float* b1  = (const float*)d_in[9];
    const float* W2  = (const float*)d_in[10];
    const float* b2  = (const float*)d_in[11];
    float* out = (float*)d_out;
    u16* ws = (u16*)d_ws;

    hipLaunchKernelGGL(prep_w, dim3(128), dim3(256), 0, stream,
                       Wq, Wk, Wv, W1, W2, ws);
    hipLaunchKernelGGL(ta_fused_kernel, dim3(Bb * Nn / NT), dim3(256), 0, stream,
                       x, ste, bq, bk, bv, b1, b2, ws, out);
}